// Round 3
// baseline (6386.307 us; speedup 1.0000x reference)
//
#include <hip/hip_runtime.h>

// Fused 2-layer LSTM, bf16 MFMA recurrence, weights resident in VGPRs/AGPRs.
// 16 blocks x 512 threads; block b owns batches [16b, 16b+16).
// Per wave w (8 waves): gate-row tiles {q*8+w}, q=0..3 => i/f/g/o rows of
// h-columns [w*16, w*16+16) -> elementwise is lane-local on MFMA D-frags.
// R3: ONE barrier per step — L1 pipelined one step behind L0. Iteration t
// computes L0(t) and L1(t-1); both consume only pre-barrier state
// {h0(t-1), h1(t-2), x(t)}. 52 MFMAs + 8 ew chains merged per phase.

typedef short bf16x8 __attribute__((ext_vector_type(8)));
typedef float f32x4 __attribute__((ext_vector_type(4)));

static constexpr int CIN = 12, T = 2048, H = 128;
static constexpr int BPB = 16, NTHR = 512, NBLK = 16;
static constexpr float L2E = 1.4426950408889634f;

// LDS byte map
static constexpr int LDS_H0  = 0;      // 2 x 4096  (h0 double buffer, B-frag layout)
static constexpr int LDS_H1  = 8192;   // 2 x 4096  (h1 double buffer)
static constexpr int LDS_X   = 16384;  // 2 x 1024  (x_t, k=12 col == 1.0 -> L0 bias)
static constexpr int LDS_RED = 18432;  // 512 f32 reduction scratch (epilogue)
static constexpr int LDS_SZ  = 20480;

#if __has_builtin(__builtin_amdgcn_exp2f)
#define EXP2(x) __builtin_amdgcn_exp2f(x)
#else
#define EXP2(x) exp2f(x)
#endif

__device__ __forceinline__ unsigned f2bf(float f) {  // f32 -> bf16 bits, RTNE (prologue only)
  unsigned u = __builtin_bit_cast(unsigned, f);
  return (u + 0x7FFFu + ((u >> 16) & 1u)) >> 16;
}

__device__ __forceinline__ unsigned cvtpk_bf16(float lo, float hi) {
  unsigned r;
  asm("v_cvt_pk_bf16_f32 %0, %1, %2" : "=v"(r) : "v"(lo), "v"(hi));
  return r;
}

__device__ __forceinline__ float sig_pre(float a) {  // 1/(1+2^a)
  return __builtin_amdgcn_rcpf(1.f + EXP2(a));
}

__global__ __launch_bounds__(NTHR, 2) void lstm_fused(
    const float* __restrict__ xg,
    const float* __restrict__ Wih0, const float* __restrict__ Whh0,
    const float* __restrict__ bih0, const float* __restrict__ bhh0,
    const float* __restrict__ Wih1, const float* __restrict__ Whh1,
    const float* __restrict__ bih1, const float* __restrict__ bhh1,
    const float* __restrict__ Wd,   const float* __restrict__ bd,
    float* __restrict__ out)
{
  __shared__ char lds[LDS_SZ];
  const int tid = threadIdx.x;
  const int l  = tid & 63;
  const int w  = tid >> 6;   // wave 0..7
  const int lg = l >> 4;     // lane group 0..3 (k-chunk)
  const int lr = l & 15;     // A: row-in-tile ; B/D: batch column
  const int b0 = blockIdx.x * BPB;

  // ---- zero LDS (x pad region + initial h0/h1 state = 0) ----
  for (int i = tid; i < LDS_SZ / 4; i += NTHR) ((int*)lds)[i] = 0;
  __syncthreads();
  // constant-1.0 column at k==12 of both X buffers (feeds L0 bias row in A)
  if (tid < 32) {
    const int buf = tid >> 4, b = tid & 15;
    *(unsigned short*)(lds + LDS_X + buf * 1024 + 256 + b * 16 + 8) = 0x3F80;
  }

  // ---- load weight A-fragments (pre-scaled: i,f,o rows *-log2e ; g rows *2log2e) ----
  bf16x8 A0[4][5];  // layer0: K = [h0(128) ; x(12) ; 1 ; pad] -> 5 kfrags
  bf16x8 A1[4][8];  // layer1: K = [h1(128) ; h0(128)]        -> 8 kfrags
  f32x4 b1r[4];     // layer1 bias as MFMA C-init (D-frag layout: row = lg*4+r)
  #pragma unroll
  for (int q = 0; q < 4; ++q) {
    const int n = (q * 8 + w) * 16 + lr;         // global gate row 0..511
    const float s = (q == 2) ? (2.f * L2E) : (-L2E);
    #pragma unroll
    for (int kf = 0; kf < 4; ++kf) {
      const float* src = &Whh0[n * H + kf * 32 + lg * 8];
      #pragma unroll
      for (int j = 0; j < 8; ++j) A0[q][kf][j] = (short)f2bf(src[j] * s);
    }
    #pragma unroll
    for (int j = 0; j < 8; ++j) {
      const int k = lg * 8 + j;
      float v = 0.f;
      if (k < CIN) v = Wih0[n * CIN + k] * s;
      else if (k == CIN) v = (bih0[n] + bhh0[n]) * s;   // bias column, pairs with 1.0 in X
      A0[q][4][j] = (short)f2bf(v);
    }
    #pragma unroll
    for (int kf = 0; kf < 4; ++kf) {
      const float* srcA = &Whh1[n * H + kf * 32 + lg * 8];
      const float* srcB = &Wih1[n * H + kf * 32 + lg * 8];
      #pragma unroll
      for (int j = 0; j < 8; ++j) {
        A1[q][kf][j]     = (short)f2bf(srcA[j] * s);
        A1[q][4 + kf][j] = (short)f2bf(srcB[j] * s);
      }
    }
    #pragma unroll
    for (int r = 0; r < 4; ++r) {
      const int nd = (q * 8 + w) * 16 + lg * 4 + r;  // D-frag row for this lane
      b1r[q][r] = (bih1[nd] + bhh1[nd]) * s;
    }
  }
  const f32x4 zed = {0.f, 0.f, 0.f, 0.f};

  // per-lane LDS addresses
  const int rdB  = lg * 256 + lr * 16;                       // B-frag read base
  const int bcol = w * 16 + lg * 4;                          // base h-column (4 per lane)
  const int wrH  = (bcol >> 3) * 256 + lr * 16 + (bcol & 7) * 2;
  const int xb = tid & 15, xc = tid >> 4;                    // x loader role (tid<192)
  const int wrX = (xc >> 3) * 256 + xb * 16 + (xc & 7) * 2;
  const size_t xbase = (size_t)(b0 + xb) * (CIN * T) + (size_t)xc * T;

  // x(t=0) into X[0]
  if (tid < 192)
    *(unsigned short*)(lds + LDS_X + wrX) = (unsigned short)f2bf(xg[xbase]);
  __syncthreads();

  float c0v[4] = {0.f, 0.f, 0.f, 0.f};
  float c1v[4] = {0.f, 0.f, 0.f, 0.f};
  float h1v[4] = {0.f, 0.f, 0.f, 0.f};

  // Iteration t: L0 step t (h0(t) <- h0(t-1), x(t)) and L1 step t-1
  // (h1(t-1) <- h1(t-2), h0(t-1)). Buffers: read H0[1-p], H1[p], X[p];
  // write H0[p], H1[1-p], X[1-p]. One barrier.
  #pragma unroll 2
  for (int t = 0; t < T; ++t) {
    const int p = t & 1;
    float xnext = 0.f;
    if (tid < 192) xnext = xg[xbase + (t + 1 < T ? t + 1 : t)];

    // ---- load all B-fragments for this phase ----
    bf16x8 bfH0[4], bfH1[4], bfX;
    #pragma unroll
    for (int kf = 0; kf < 4; ++kf) {
      bfH0[kf] = *(const bf16x8*)(lds + LDS_H0 + (1 - p) * 4096 + kf * 1024 + rdB);
      bfH1[kf] = *(const bf16x8*)(lds + LDS_H1 + p * 4096 + kf * 1024 + rdB);
    }
    bfX = *(const bf16x8*)(lds + LDS_X + p * 1024 + rdB);

    // ---- merged MFMA block: L0 (20) + L1 (32) ----
    f32x4 accA[4], accB[4];
    #pragma unroll
    for (int q = 0; q < 4; ++q) { accA[q] = zed; accB[q] = b1r[q]; }
    #pragma unroll
    for (int kf = 0; kf < 4; ++kf) {
      #pragma unroll
      for (int q = 0; q < 4; ++q) {
        accA[q] = __builtin_amdgcn_mfma_f32_16x16x32_bf16(A0[q][kf], bfH0[kf], accA[q], 0, 0, 0);
        accB[q] = __builtin_amdgcn_mfma_f32_16x16x32_bf16(A1[q][kf], bfH1[kf], accB[q], 0, 0, 0);
        accB[q] = __builtin_amdgcn_mfma_f32_16x16x32_bf16(A1[q][4 + kf], bfH0[kf], accB[q], 0, 0, 0);
      }
    }
    #pragma unroll
    for (int q = 0; q < 4; ++q)
      accA[q] = __builtin_amdgcn_mfma_f32_16x16x32_bf16(A0[q][4], bfX, accA[q], 0, 0, 0);

    // ---- elementwise L0 -> h0(t) ----
    {
      float h0t[4];
      #pragma unroll
      for (int r = 0; r < 4; ++r) {
        const float iv = sig_pre(accA[0][r]);
        const float fv = sig_pre(accA[1][r]);
        const float gv = fmaf(-2.f, sig_pre(accA[2][r]), 1.f);
        const float ov = sig_pre(accA[3][r]);
        const float c  = fmaf(fv, c0v[r], iv * gv);
        c0v[r] = c;
        const float th = fmaf(-2.f, sig_pre(c * (2.f * L2E)), 1.f);
        h0t[r] = ov * th;
      }
      const unsigned hp0 = cvtpk_bf16(h0t[0], h0t[1]);
      const unsigned hp1 = cvtpk_bf16(h0t[2], h0t[3]);
      *(unsigned long long*)(lds + LDS_H0 + p * 4096 + wrH) =
          ((unsigned long long)hp1 << 32) | hp0;
    }

    // ---- elementwise L1 -> h1(t-1) (skip at t==0: keep h1(-1)=0) ----
    if (t > 0) {
      #pragma unroll
      for (int r = 0; r < 4; ++r) {
        const float iv = sig_pre(accB[0][r]);
        const float fv = sig_pre(accB[1][r]);
        const float gv = fmaf(-2.f, sig_pre(accB[2][r]), 1.f);
        const float ov = sig_pre(accB[3][r]);
        const float c  = fmaf(fv, c1v[r], iv * gv);
        c1v[r] = c;
        const float th = fmaf(-2.f, sig_pre(c * (2.f * L2E)), 1.f);
        h1v[r] = ov * th;
      }
      const unsigned hp0 = cvtpk_bf16(h1v[0], h1v[1]);
      const unsigned hp1 = cvtpk_bf16(h1v[2], h1v[3]);
      *(unsigned long long*)(lds + LDS_H1 + (1 - p) * 4096 + wrH) =
          ((unsigned long long)hp1 << 32) | hp0;
    }

    if (tid < 192) {
      const unsigned xp = cvtpk_bf16(xnext, xnext);
      *(unsigned short*)(lds + LDS_X + (1 - p) * 1024 + wrX) = (unsigned short)xp;
    }
    __syncthreads();
  }

  // ---- peeled final L1 step (t=T): h1(T-1) <- h1(T-2), h0(T-1) ----
  // T even: h0(T-1) in H0[1], h1(T-2) in H1[0].
  {
    bf16x8 bfH0[4], bfH1[4];
    #pragma unroll
    for (int kf = 0; kf < 4; ++kf) {
      bfH0[kf] = *(const bf16x8*)(lds + LDS_H0 + 4096 + kf * 1024 + rdB);
      bfH1[kf] = *(const bf16x8*)(lds + LDS_H1 + kf * 1024 + rdB);
    }
    f32x4 accB[4];
    #pragma unroll
    for (int q = 0; q < 4; ++q) accB[q] = b1r[q];
    #pragma unroll
    for (int kf = 0; kf < 4; ++kf) {
      #pragma unroll
      for (int q = 0; q < 4; ++q) {
        accB[q] = __builtin_amdgcn_mfma_f32_16x16x32_bf16(A1[q][kf], bfH1[kf], accB[q], 0, 0, 0);
        accB[q] = __builtin_amdgcn_mfma_f32_16x16x32_bf16(A1[q][4 + kf], bfH0[kf], accB[q], 0, 0, 0);
      }
    }
    #pragma unroll
    for (int r = 0; r < 4; ++r) {
      const float iv = sig_pre(accB[0][r]);
      const float fv = sig_pre(accB[1][r]);
      const float gv = fmaf(-2.f, sig_pre(accB[2][r]), 1.f);
      const float ov = sig_pre(accB[3][r]);
      const float c  = fmaf(fv, c1v[r], iv * gv);
      c1v[r] = c;
      const float th = fmaf(-2.f, sig_pre(c * (2.f * L2E)), 1.f);
      h1v[r] = ov * th;
    }
  }

  // ---- epilogue: feats = h1(T-1) (f32 from regs), scores = sigmoid(h1.Wd + bd) ----
  const float4 wd = *(const float4*)&Wd[bcol];
  const float partial = h1v[0] * wd.x + h1v[1] * wd.y + h1v[2] * wd.z + h1v[3] * wd.w;
  #pragma unroll
  for (int r = 0; r < 4; ++r)
    out[256 + (size_t)(b0 + lr) * H + (bcol + r)] = h1v[r];
  ((float*)(lds + LDS_RED))[tid] = partial;
  __syncthreads();
  if (tid < 16) {
    float s = 0.f;
    #pragma unroll 8
    for (int k = 0; k < 32; ++k) s += ((float*)(lds + LDS_RED))[tid + 16 * k];
    const float v = s + bd[0];
    out[b0 + tid] = __builtin_amdgcn_rcpf(1.f + EXP2(-v * L2E));
  }
}

extern "C" void kernel_launch(void* const* d_in, const int* in_sizes, int n_in,
                              void* d_out, int out_size, void* d_ws, size_t ws_size,
                              hipStream_t stream) {
  const float* x    = (const float*)d_in[0];
  // d_in[1] = seq_lengths : unused by the reference
  const float* Wih0 = (const float*)d_in[2];
  const float* Whh0 = (const float*)d_in[3];
  const float* bih0 = (const float*)d_in[4];
  const float* bhh0 = (const float*)d_in[5];
  const float* Wih1 = (const float*)d_in[6];
  const float* Whh1 = (const float*)d_in[7];
  const float* bih1 = (const float*)d_in[8];
  const float* bhh1 = (const float*)d_in[9];
  const float* Wd   = (const float*)d_in[10];
  const float* bd   = (const float*)d_in[11];
  (void)in_sizes; (void)n_in; (void)out_size; (void)d_ws; (void)ws_size;

  lstm_fused<<<dim3(NBLK), dim3(NTHR), 0, stream>>>(
      x, Wih0, Whh0, bih0, bhh0, Wih1, Whh1, bih1, bhh1, Wd, bd, (float*)d_out);
}

// Round 4
// 5178.320 us; speedup vs baseline: 1.2333x; 1.2333x over previous
//
#include <hip/hip_runtime.h>

// R4: layer-split producer/consumer LSTM.
//  - 32 blocks x 512 threads. Blocks 0..15: layer-0 producers (batches 16i..16i+15).
//    Blocks 16..31: layer-1 consumers for the same batch group (pair = blockIdx-16).
//  - Producer streams h0(t) (bf16, B-frag image, 4KB/step) through a ring in d_ws.
//    Monotone prod/cons counters, agent-scope release/acquire, zeroed per launch
//    by lstm_zero_flags (graph-replay/poison safe). Flow control: RING=8 slots.
//  - Consumer prefetches h0(t+1) during step t -> L2/L3 latency hidden under MFMA.
//  - Fallback: proven R2 single-kernel path if ws_size too small.

typedef short bf16x8 __attribute__((ext_vector_type(8)));
typedef float f32x4 __attribute__((ext_vector_type(4)));

static constexpr int CIN = 12, T = 2048, H = 128;
static constexpr int BPB = 16, NTHR = 512;
static constexpr float L2E = 1.4426950408889634f;

static constexpr int RING = 8;                    // ring slots per pair
static constexpr size_t SLOT_BYTES = 4096;        // 16 batches x 128 cols x 2B
static constexpr size_t FLAG_BYTES = 8192;        // prod[16]+cons[16], 256B stride
static constexpr size_t WS_NEED = FLAG_BYTES + 16ull * RING * SLOT_BYTES;

#if __has_builtin(__builtin_amdgcn_exp2f)
#define EXP2(x) __builtin_amdgcn_exp2f(x)
#else
#define EXP2(x) exp2f(x)
#endif

__device__ __forceinline__ unsigned f2bf(float f) {  // f32 -> bf16 bits, RTNE (prologue only)
  unsigned u = __builtin_bit_cast(unsigned, f);
  return (u + 0x7FFFu + ((u >> 16) & 1u)) >> 16;
}

__device__ __forceinline__ unsigned cvtpk_bf16(float lo, float hi) {
  unsigned r;
  asm("v_cvt_pk_bf16_f32 %0, %1, %2" : "=v"(r) : "v"(lo), "v"(hi));
  return r;
}

__device__ __forceinline__ float sig_pre(float a) {  // 1/(1+2^a)
  return __builtin_amdgcn_rcpf(1.f + EXP2(a));
}

// Gate math on a D-fragment (4 rows/lane). Weights pre-scaled so every gate is
// exp2-based: i,f,o rows * -log2e ; g rows * 2log2e. Updates c[], h[]; returns
// packed 4x bf16 of h.
__device__ __forceinline__ unsigned long long lstm_ew(
    const f32x4& a0, const f32x4& a1, const f32x4& a2, const f32x4& a3,
    float* cv, float* hv) {
  #pragma unroll
  for (int r = 0; r < 4; ++r) {
    const float iv = sig_pre(a0[r]);
    const float fv = sig_pre(a1[r]);
    const float gv = fmaf(-2.f, sig_pre(a2[r]), 1.f);
    const float ov = sig_pre(a3[r]);
    const float c  = fmaf(fv, cv[r], iv * gv);
    cv[r] = c;
    const float th = fmaf(-2.f, sig_pre(c * (2.f * L2E)), 1.f);
    hv[r] = ov * th;
  }
  const unsigned hp0 = cvtpk_bf16(hv[0], hv[1]);
  const unsigned hp1 = cvtpk_bf16(hv[2], hv[3]);
  return ((unsigned long long)hp1 << 32) | hp0;
}

__device__ __forceinline__ void wait_ge(unsigned* p, unsigned tgt) {
  while (__hip_atomic_load(p, __ATOMIC_ACQUIRE, __HIP_MEMORY_SCOPE_AGENT) < tgt)
    __builtin_amdgcn_s_sleep(2);
}

__global__ void lstm_zero_flags(unsigned* f) {
  f[blockIdx.x * 256 + threadIdx.x] = 0;  // 8 blocks x 256 = 2048 ints = 8KB
}

// ============================ split kernel ============================
__global__ __launch_bounds__(NTHR, 2) void lstm_split(
    const float* __restrict__ xg,
    const float* __restrict__ Wih0, const float* __restrict__ Whh0,
    const float* __restrict__ bih0, const float* __restrict__ bhh0,
    const float* __restrict__ Wih1, const float* __restrict__ Whh1,
    const float* __restrict__ bih1, const float* __restrict__ bhh1,
    const float* __restrict__ Wd,   const float* __restrict__ bd,
    float* __restrict__ out, char* __restrict__ ws)
{
  __shared__ char lds[12288];
  const int tid = threadIdx.x;
  const int l  = tid & 63;
  const int w  = tid >> 6;   // wave 0..7
  const int lg = l >> 4;     // lane group 0..3 (k-chunk)
  const int lr = l & 15;     // A: row-in-tile ; B/D: batch column
  const bool producer = (blockIdx.x < 16);
  const int pair = blockIdx.x & 15;
  const int b0 = pair * BPB;

  unsigned* prodf = (unsigned*)ws + pair * 64;          // 256B stride
  unsigned* consf = (unsigned*)ws + 1024 + pair * 64;
  char* ring = ws + FLAG_BYTES + (size_t)pair * RING * SLOT_BYTES;

  // zero LDS (h-state buffers start at 0)
  for (int i = tid; i < 12288 / 4; i += NTHR) ((int*)lds)[i] = 0;
  __syncthreads();

  // shared per-lane geometry
  const int rdB  = lg * 256 + lr * 16;                  // B-frag read base
  const int bcol = w * 16 + lg * 4;                     // base h-column (4/lane)
  const int wrH  = (bcol >> 3) * 256 + lr * 16 + (bcol & 7) * 2;

  if (producer) {
    // ---------------- LAYER 0 PRODUCER ----------------
    // LDS: H0 dbuf at 0 (2x4096), X dbuf at 8192 (2x1024)
    constexpr int LDS_XP = 8192;
    // constant-1.0 column at k==12 of both X buffers (bias row of A0 pairs with it)
    if (tid < 32) {
      const int buf = tid >> 4, b = tid & 15;
      *(unsigned short*)(lds + LDS_XP + buf * 1024 + 256 + b * 16 + 8) = 0x3F80;
    }

    bf16x8 A0[4][5];
    #pragma unroll
    for (int q = 0; q < 4; ++q) {
      const int n = (q * 8 + w) * 16 + lr;
      const float s = (q == 2) ? (2.f * L2E) : (-L2E);
      #pragma unroll
      for (int kf = 0; kf < 4; ++kf) {
        const float* src = &Whh0[n * H + kf * 32 + lg * 8];
        #pragma unroll
        for (int j = 0; j < 8; ++j) A0[q][kf][j] = (short)f2bf(src[j] * s);
      }
      #pragma unroll
      for (int j = 0; j < 8; ++j) {
        const int k = lg * 8 + j;
        float v = 0.f;
        if (k < CIN) v = Wih0[n * CIN + k] * s;
        else if (k == CIN) v = (bih0[n] + bhh0[n]) * s;
        A0[q][4][j] = (short)f2bf(v);
      }
    }
    const f32x4 zed = {0.f, 0.f, 0.f, 0.f};

    const int xb = tid & 15, xc = tid >> 4;             // x loader role (tid<192)
    const int wrX = (xc >> 3) * 256 + xb * 16 + (xc & 7) * 2;
    const size_t xbase = (size_t)(b0 + xb) * (CIN * T) + (size_t)xc * T;
    if (tid < 192)
      *(unsigned short*)(lds + LDS_XP + wrX) = (unsigned short)f2bf(xg[xbase]);
    __syncthreads();

    float c0v[4] = {0.f, 0.f, 0.f, 0.f};
    float h0t[4];
    unsigned cons_seen = 0;

    #pragma unroll 2
    for (int t = 0; t < T; ++t) {
      const int p = t & 1;
      if (t >= RING) {                                  // flow control (R slots)
        const unsigned tgt = (unsigned)(t - RING + 1);
        if (cons_seen < tgt) { wait_ge(consf, tgt); cons_seen = tgt; }
      }
      float xnext = 0.f;
      if (tid < 192) xnext = xg[xbase + (t + 1 < T ? t + 1 : t)];

      bf16x8 bfH0[4], bfX;
      #pragma unroll
      for (int kf = 0; kf < 4; ++kf)
        bfH0[kf] = *(const bf16x8*)(lds + p * 4096 + kf * 1024 + rdB);
      bfX = *(const bf16x8*)(lds + LDS_XP + p * 1024 + rdB);

      f32x4 acc[4];
      #pragma unroll
      for (int q = 0; q < 4; ++q) acc[q] = zed;
      #pragma unroll
      for (int kf = 0; kf < 4; ++kf) {
        #pragma unroll
        for (int q = 0; q < 4; ++q)
          acc[q] = __builtin_amdgcn_mfma_f32_16x16x32_bf16(A0[q][kf], bfH0[kf], acc[q], 0, 0, 0);
      }
      #pragma unroll
      for (int q = 0; q < 4; ++q)
        acc[q] = __builtin_amdgcn_mfma_f32_16x16x32_bf16(A0[q][4], bfX, acc[q], 0, 0, 0);

      const unsigned long long hv64 = lstm_ew(acc[0], acc[1], acc[2], acc[3], c0v, h0t);
      *(unsigned long long*)(lds + (1 - p) * 4096 + wrH) = hv64;          // local dbuf
      *(unsigned long long*)(ring + (size_t)(t & (RING - 1)) * SLOT_BYTES + wrH) = hv64;  // stream

      if (tid < 192) {
        const unsigned xp = cvtpk_bf16(xnext, xnext);
        *(unsigned short*)(lds + LDS_XP + (1 - p) * 1024 + wrX) = (unsigned short)xp;
      }
      __syncthreads();
      if (tid == 0)
        __hip_atomic_store(prodf, (unsigned)(t + 1), __ATOMIC_RELEASE, __HIP_MEMORY_SCOPE_AGENT);
    }
    return;
  }

  // ---------------- LAYER 1 CONSUMER ----------------
  // LDS: H1 dbuf at 0 (2x4096), RED at 8192 (2KB)
  bf16x8 A1[4][8];
  f32x4 b1r[4];
  #pragma unroll
  for (int q = 0; q < 4; ++q) {
    const int n = (q * 8 + w) * 16 + lr;
    const float s = (q == 2) ? (2.f * L2E) : (-L2E);
    #pragma unroll
    for (int kf = 0; kf < 4; ++kf) {
      const float* srcA = &Whh1[n * H + kf * 32 + lg * 8];
      const float* srcB = &Wih1[n * H + kf * 32 + lg * 8];
      #pragma unroll
      for (int j = 0; j < 8; ++j) {
        A1[q][kf][j]     = (short)f2bf(srcA[j] * s);
        A1[q][4 + kf][j] = (short)f2bf(srcB[j] * s);
      }
    }
    #pragma unroll
    for (int r = 0; r < 4; ++r) {
      const int nd = (q * 8 + w) * 16 + lg * 4 + r;     // D-frag row for this lane
      b1r[q][r] = (bih1[nd] + bhh1[nd]) * s;
    }
  }
  __syncthreads();

  float c1v[4] = {0.f, 0.f, 0.f, 0.f};
  float h1v[4] = {0.f, 0.f, 0.f, 0.f};
  unsigned prod_seen = 0;

  // warm-up: h0(0)
  wait_ge(prodf, 1); prod_seen = 1;
  bf16x8 h0A[4], h0B[4];
  #pragma unroll
  for (int kf = 0; kf < 4; ++kf)
    h0A[kf] = *(const bf16x8*)(ring + kf * 1024 + rdB);

#define CONS_STEP(TT, P, CUR, NXT)                                              \
  do {                                                                          \
    const int t_ = (TT);                                                        \
    const unsigned need = (unsigned)(((t_ + 2) <= T) ? (t_ + 2) : T);           \
    if (prod_seen < need) { wait_ge(prodf, need); prod_seen = need; }           \
    {                                                                           \
      const int tn = (t_ + 1 < T) ? (t_ + 1) : (T - 1);                         \
      const char* nb = ring + (size_t)(tn & (RING - 1)) * SLOT_BYTES;           \
      _Pragma("unroll")                                                         \
      for (int kf = 0; kf < 4; ++kf)                                            \
        NXT[kf] = *(const bf16x8*)(nb + kf * 1024 + rdB);                       \
    }                                                                           \
    bf16x8 bh1[4];                                                              \
    _Pragma("unroll")                                                           \
    for (int kf = 0; kf < 4; ++kf)                                              \
      bh1[kf] = *(const bf16x8*)(lds + (P) * 4096 + kf * 1024 + rdB);           \
    f32x4 acc[4];                                                               \
    _Pragma("unroll")                                                           \
    for (int q = 0; q < 4; ++q) acc[q] = b1r[q];                                \
    _Pragma("unroll")                                                           \
    for (int kf = 0; kf < 4; ++kf) {                                            \
      _Pragma("unroll")                                                         \
      for (int q = 0; q < 4; ++q) {                                             \
        acc[q] = __builtin_amdgcn_mfma_f32_16x16x32_bf16(A1[q][kf], bh1[kf], acc[q], 0, 0, 0); \
        acc[q] = __builtin_amdgcn_mfma_f32_16x16x32_bf16(A1[q][4 + kf], CUR[kf], acc[q], 0, 0, 0); \
      }                                                                         \
    }                                                                           \
    const unsigned long long hv64 = lstm_ew(acc[0], acc[1], acc[2], acc[3], c1v, h1v); \
    *(unsigned long long*)(lds + (1 - (P)) * 4096 + wrH) = hv64;                \
    __syncthreads();                                                            \
    if (tid == 0 && (P) == 1)                                                   \
      __hip_atomic_store(consf, (unsigned)(t_ + 1), __ATOMIC_RELEASE, __HIP_MEMORY_SCOPE_AGENT); \
  } while (0)

  for (int t = 0; t < T; t += 2) {
    CONS_STEP(t,     0, h0A, h0B);
    CONS_STEP(t + 1, 1, h0B, h0A);
  }
#undef CONS_STEP

  // ---- epilogue: feats = h1(T-1), scores = sigmoid(h1 . Wd + bd) ----
  const float4 wd = *(const float4*)&Wd[bcol];
  const float partial = h1v[0] * wd.x + h1v[1] * wd.y + h1v[2] * wd.z + h1v[3] * wd.w;
  #pragma unroll
  for (int r = 0; r < 4; ++r)
    out[256 + (size_t)(b0 + lr) * H + (bcol + r)] = h1v[r];
  ((float*)(lds + 8192))[tid] = partial;
  __syncthreads();
  if (tid < 16) {
    float s = 0.f;
    #pragma unroll 8
    for (int k = 0; k < 32; ++k) s += ((float*)(lds + 8192))[tid + 16 * k];
    const float v = s + bd[0];
    out[b0 + tid] = __builtin_amdgcn_rcpf(1.f + EXP2(-v * L2E));
  }
}

// ============================ fallback: R2 single kernel ============================
__global__ __launch_bounds__(NTHR, 2) void lstm_single(
    const float* __restrict__ xg,
    const float* __restrict__ Wih0, const float* __restrict__ Whh0,
    const float* __restrict__ bih0, const float* __restrict__ bhh0,
    const float* __restrict__ Wih1, const float* __restrict__ Whh1,
    const float* __restrict__ bih1, const float* __restrict__ bhh1,
    const float* __restrict__ Wd,   const float* __restrict__ bd,
    float* __restrict__ out)
{
  constexpr int LDS_H0 = 0, LDS_H1 = 8192, LDS_X = 16384, LDS_RED = 18432, LDS_SZ = 20480;
  __shared__ char lds[LDS_SZ];
  const int tid = threadIdx.x;
  const int l  = tid & 63;
  const int w  = tid >> 6;
  const int lg = l >> 4;
  const int lr = l & 15;
  const int b0 = blockIdx.x * BPB;

  for (int i = tid; i < LDS_SZ / 4; i += NTHR) ((int*)lds)[i] = 0;
  __syncthreads();
  if (tid < 32) {
    const int buf = tid >> 4, b = tid & 15;
    *(unsigned short*)(lds + LDS_X + buf * 1024 + 256 + b * 16 + 8) = 0x3F80;
  }

  bf16x8 A0[4][5];
  bf16x8 A1[4][8];
  f32x4 b1r[4];
  #pragma unroll
  for (int q = 0; q < 4; ++q) {
    const int n = (q * 8 + w) * 16 + lr;
    const float s = (q == 2) ? (2.f * L2E) : (-L2E);
    #pragma unroll
    for (int kf = 0; kf < 4; ++kf) {
      const float* src = &Whh0[n * H + kf * 32 + lg * 8];
      #pragma unroll
      for (int j = 0; j < 8; ++j) A0[q][kf][j] = (short)f2bf(src[j] * s);
    }
    #pragma unroll
    for (int j = 0; j < 8; ++j) {
      const int k = lg * 8 + j;
      float v = 0.f;
      if (k < CIN) v = Wih0[n * CIN + k] * s;
      else if (k == CIN) v = (bih0[n] + bhh0[n]) * s;
      A0[q][4][j] = (short)f2bf(v);
    }
    #pragma unroll
    for (int kf = 0; kf < 4; ++kf) {
      const float* srcA = &Whh1[n * H + kf * 32 + lg * 8];
      const float* srcB = &Wih1[n * H + kf * 32 + lg * 8];
      #pragma unroll
      for (int j = 0; j < 8; ++j) {
        A1[q][kf][j]     = (short)f2bf(srcA[j] * s);
        A1[q][4 + kf][j] = (short)f2bf(srcB[j] * s);
      }
    }
    #pragma unroll
    for (int r = 0; r < 4; ++r) {
      const int nd = (q * 8 + w) * 16 + lg * 4 + r;
      b1r[q][r] = (bih1[nd] + bhh1[nd]) * s;
    }
  }
  const f32x4 zed = {0.f, 0.f, 0.f, 0.f};

  const int rdB  = lg * 256 + lr * 16;
  const int bcol = w * 16 + lg * 4;
  const int wrH  = (bcol >> 3) * 256 + lr * 16 + (bcol & 7) * 2;
  const int xb = tid & 15, xc = tid >> 4;
  const int wrX = (xc >> 3) * 256 + xb * 16 + (xc & 7) * 2;
  const size_t xbase = (size_t)(b0 + xb) * (CIN * T) + (size_t)xc * T;

  if (tid < 192)
    *(unsigned short*)(lds + LDS_X + wrX) = (unsigned short)f2bf(xg[xbase]);
  __syncthreads();

  float c0v[4] = {0.f, 0.f, 0.f, 0.f};
  float c1v[4] = {0.f, 0.f, 0.f, 0.f};
  float h1v[4] = {0.f, 0.f, 0.f, 0.f};
  float h0t[4];

  #pragma unroll 2
  for (int t = 0; t < T; ++t) {
    const int p = t & 1;
    float xnext = 0.f;
    if (tid < 192) xnext = xg[xbase + (t + 1 < T ? t + 1 : t)];

    f32x4 acc[4];
    #pragma unroll
    for (int q = 0; q < 4; ++q) acc[q] = zed;
    #pragma unroll
    for (int kf = 0; kf < 5; ++kf) {
      const int src = (kf < 4) ? (LDS_H0 + p * 4096 + kf * 1024 + rdB)
                               : (LDS_X + p * 1024 + rdB);
      const bf16x8 bf = *(const bf16x8*)(lds + src);
      #pragma unroll
      for (int q = 0; q < 4; ++q)
        acc[q] = __builtin_amdgcn_mfma_f32_16x16x32_bf16(A0[q][kf], bf, acc[q], 0, 0, 0);
    }
    *(unsigned long long*)(lds + LDS_H0 + (1 - p) * 4096 + wrH) =
        lstm_ew(acc[0], acc[1], acc[2], acc[3], c0v, h0t);
    if (tid < 192) {
      const unsigned xp = cvtpk_bf16(xnext, xnext);
      *(unsigned short*)(lds + LDS_X + (1 - p) * 1024 + wrX) = (unsigned short)xp;
    }
    __syncthreads();

    #pragma unroll
    for (int q = 0; q < 4; ++q) acc[q] = b1r[q];
    #pragma unroll
    for (int kf = 0; kf < 8; ++kf) {
      const int src = (kf < 4)
          ? (LDS_H1 + p * 4096 + kf * 1024 + rdB)
          : (LDS_H0 + (1 - p) * 4096 + (kf - 4) * 1024 + rdB);
      const bf16x8 bf = *(const bf16x8*)(lds + src);
      #pragma unroll
      for (int q = 0; q < 4; ++q)
        acc[q] = __builtin_amdgcn_mfma_f32_16x16x32_bf16(A1[q][kf], bf, acc[q], 0, 0, 0);
    }
    *(unsigned long long*)(lds + LDS_H1 + (1 - p) * 4096 + wrH) =
        lstm_ew(acc[0], acc[1], acc[2], acc[3], c1v, h1v);
    __syncthreads();
  }

  const float4 wd = *(const float4*)&Wd[bcol];
  const float partial = h1v[0] * wd.x + h1v[1] * wd.y + h1v[2] * wd.z + h1v[3] * wd.w;
  #pragma unroll
  for (int r = 0; r < 4; ++r)
    out[256 + (size_t)(b0 + lr) * H + (bcol + r)] = h1v[r];
  ((float*)(lds + LDS_RED))[tid] = partial;
  __syncthreads();
  if (tid < 16) {
    float s = 0.f;
    #pragma unroll 8
    for (int k = 0; k < 32; ++k) s += ((float*)(lds + LDS_RED))[tid + 16 * k];
    const float v = s + bd[0];
    out[b0 + tid] = __builtin_amdgcn_rcpf(1.f + EXP2(-v * L2E));
  }
}

extern "C" void kernel_launch(void* const* d_in, const int* in_sizes, int n_in,
                              void* d_out, int out_size, void* d_ws, size_t ws_size,
                              hipStream_t stream) {
  const float* x    = (const float*)d_in[0];
  // d_in[1] = seq_lengths : unused by the reference
  const float* Wih0 = (const float*)d_in[2];
  const float* Whh0 = (const float*)d_in[3];
  const float* bih0 = (const float*)d_in[4];
  const float* bhh0 = (const float*)d_in[5];
  const float* Wih1 = (const float*)d_in[6];
  const float* Whh1 = (const float*)d_in[7];
  const float* bih1 = (const float*)d_in[8];
  const float* bhh1 = (const float*)d_in[9];
  const float* Wd   = (const float*)d_in[10];
  const float* bd   = (const float*)d_in[11];
  (void)in_sizes; (void)n_in; (void)out_size;

  if (ws_size >= WS_NEED && d_ws != nullptr) {
    lstm_zero_flags<<<dim3(8), dim3(256), 0, stream>>>((unsigned*)d_ws);
    lstm_split<<<dim3(32), dim3(NTHR), 0, stream>>>(
        x, Wih0, Whh0, bih0, bhh0, Wih1, Whh1, bih1, bhh1, Wd, bd,
        (float*)d_out, (char*)d_ws);
  } else {
    lstm_single<<<dim3(16), dim3(NTHR), 0, stream>>>(
        x, Wih0, Whh0, bih0, bhh0, Wih1, Whh1, bih1, bhh1, Wd, bd, (float*)d_out);
  }
}

// Round 5
// 4983.294 us; speedup vs baseline: 1.2815x; 1.0391x over previous
//
#include <hip/hip_runtime.h>

// R5: layer-split producer/consumer LSTM, flow control off the critical path.
//  - 32 blocks x 512 threads. Blocks 0..15: layer-0 producers (batches 16i..16i+15).
//    Blocks 16..31: layer-1 consumers (pair = blockIdx-16, same XCD under %8 RR).
//  - Producer streams h0(t) (bf16 B-frag image, 4KB/step) through a RING=32 ring
//    in d_ws. Producer publishes per step; consumer publishes every 8 steps only
//    (conservative flow bound) -> no per-step release on the consumer, and the
//    producer (lag ~2-3 << 32) never polls in steady state.
//  - Consumer prefetches h0(t+1) during step t (depth-1 reg prefetch).
//  - Fallback: proven R2 single-kernel path if ws_size too small.

typedef short bf16x8 __attribute__((ext_vector_type(8)));
typedef float f32x4 __attribute__((ext_vector_type(4)));

static constexpr int CIN = 12, T = 2048, H = 128;
static constexpr int BPB = 16, NTHR = 512;
static constexpr float L2E = 1.4426950408889634f;

static constexpr int RING = 32;                   // ring slots per pair
static constexpr size_t SLOT_BYTES = 4096;        // 16 batches x 128 cols x 2B
static constexpr size_t FLAG_BYTES = 8192;        // prod[16]+cons[16], 256B stride
static constexpr size_t WS_NEED = FLAG_BYTES + 16ull * RING * SLOT_BYTES;  // ~2.1MB

#if __has_builtin(__builtin_amdgcn_exp2f)
#define EXP2(x) __builtin_amdgcn_exp2f(x)
#else
#define EXP2(x) exp2f(x)
#endif

__device__ __forceinline__ unsigned f2bf(float f) {  // f32 -> bf16 bits, RTNE (prologue only)
  unsigned u = __builtin_bit_cast(unsigned, f);
  return (u + 0x7FFFu + ((u >> 16) & 1u)) >> 16;
}

__device__ __forceinline__ unsigned cvtpk_bf16(float lo, float hi) {
  unsigned r;
  asm("v_cvt_pk_bf16_f32 %0, %1, %2" : "=v"(r) : "v"(lo), "v"(hi));
  return r;
}

__device__ __forceinline__ float sig_pre(float a) {  // 1/(1+2^a)
  return __builtin_amdgcn_rcpf(1.f + EXP2(a));
}

// Gate math on a D-fragment (4 rows/lane). Weights pre-scaled so every gate is
// exp2-based: i,f,o rows * -log2e ; g rows * 2log2e. Updates c[], h[]; returns
// packed 4x bf16 of h.
__device__ __forceinline__ unsigned long long lstm_ew(
    const f32x4& a0, const f32x4& a1, const f32x4& a2, const f32x4& a3,
    float* cv, float* hv) {
  #pragma unroll
  for (int r = 0; r < 4; ++r) {
    const float iv = sig_pre(a0[r]);
    const float fv = sig_pre(a1[r]);
    const float gv = fmaf(-2.f, sig_pre(a2[r]), 1.f);
    const float ov = sig_pre(a3[r]);
    const float c  = fmaf(fv, cv[r], iv * gv);
    cv[r] = c;
    const float th = fmaf(-2.f, sig_pre(c * (2.f * L2E)), 1.f);
    hv[r] = ov * th;
  }
  const unsigned hp0 = cvtpk_bf16(hv[0], hv[1]);
  const unsigned hp1 = cvtpk_bf16(hv[2], hv[3]);
  return ((unsigned long long)hp1 << 32) | hp0;
}

__device__ __forceinline__ void wait_ge(unsigned* p, unsigned tgt) {
  while (__hip_atomic_load(p, __ATOMIC_ACQUIRE, __HIP_MEMORY_SCOPE_AGENT) < tgt)
    __builtin_amdgcn_s_sleep(2);
}

__global__ void lstm_zero_flags(unsigned* f) {
  f[blockIdx.x * 256 + threadIdx.x] = 0;  // 8 blocks x 256 = 2048 ints = 8KB
}

// ============================ split kernel ============================
__global__ __launch_bounds__(NTHR, 2) void lstm_split(
    const float* __restrict__ xg,
    const float* __restrict__ Wih0, const float* __restrict__ Whh0,
    const float* __restrict__ bih0, const float* __restrict__ bhh0,
    const float* __restrict__ Wih1, const float* __restrict__ Whh1,
    const float* __restrict__ bih1, const float* __restrict__ bhh1,
    const float* __restrict__ Wd,   const float* __restrict__ bd,
    float* __restrict__ out, char* __restrict__ ws)
{
  __shared__ char lds[12288];
  const int tid = threadIdx.x;
  const int l  = tid & 63;
  const int w  = tid >> 6;   // wave 0..7
  const int lg = l >> 4;     // lane group 0..3 (k-chunk)
  const int lr = l & 15;     // A: row-in-tile ; B/D: batch column
  const bool producer = (blockIdx.x < 16);
  const int pair = blockIdx.x & 15;
  const int b0 = pair * BPB;

  unsigned* prodf = (unsigned*)ws + pair * 64;          // 256B stride
  unsigned* consf = (unsigned*)ws + 1024 + pair * 64;
  char* ring = ws + FLAG_BYTES + (size_t)pair * RING * SLOT_BYTES;

  // zero LDS (h-state buffers start at 0)
  for (int i = tid; i < 12288 / 4; i += NTHR) ((int*)lds)[i] = 0;
  __syncthreads();

  // shared per-lane geometry
  const int rdB  = lg * 256 + lr * 16;                  // B-frag read base
  const int bcol = w * 16 + lg * 4;                     // base h-column (4/lane)
  const int wrH  = (bcol >> 3) * 256 + lr * 16 + (bcol & 7) * 2;

  if (producer) {
    // ---------------- LAYER 0 PRODUCER ----------------
    // LDS: H0 dbuf at 0 (2x4096), X dbuf at 8192 (2x1024)
    constexpr int LDS_XP = 8192;
    // constant-1.0 column at k==12 of both X buffers (bias row of A0 pairs with it)
    if (tid < 32) {
      const int buf = tid >> 4, b = tid & 15;
      *(unsigned short*)(lds + LDS_XP + buf * 1024 + 256 + b * 16 + 8) = 0x3F80;
    }

    bf16x8 A0[4][5];
    #pragma unroll
    for (int q = 0; q < 4; ++q) {
      const int n = (q * 8 + w) * 16 + lr;
      const float s = (q == 2) ? (2.f * L2E) : (-L2E);
      #pragma unroll
      for (int kf = 0; kf < 4; ++kf) {
        const float* src = &Whh0[n * H + kf * 32 + lg * 8];
        #pragma unroll
        for (int j = 0; j < 8; ++j) A0[q][kf][j] = (short)f2bf(src[j] * s);
      }
      #pragma unroll
      for (int j = 0; j < 8; ++j) {
        const int k = lg * 8 + j;
        float v = 0.f;
        if (k < CIN) v = Wih0[n * CIN + k] * s;
        else if (k == CIN) v = (bih0[n] + bhh0[n]) * s;
        A0[q][4][j] = (short)f2bf(v);
      }
    }
    const f32x4 zed = {0.f, 0.f, 0.f, 0.f};

    const int xb = tid & 15, xc = tid >> 4;             // x loader role (tid<192)
    const int wrX = (xc >> 3) * 256 + xb * 16 + (xc & 7) * 2;
    const size_t xbase = (size_t)(b0 + xb) * (CIN * T) + (size_t)xc * T;
    if (tid < 192)
      *(unsigned short*)(lds + LDS_XP + wrX) = (unsigned short)f2bf(xg[xbase]);
    __syncthreads();

    float c0v[4] = {0.f, 0.f, 0.f, 0.f};
    float h0t[4];
    unsigned cons_seen = 0;

    #pragma unroll 2
    for (int t = 0; t < T; ++t) {
      const int p = t & 1;
      if (t >= RING) {                                  // flow control (RING slots;
        const unsigned tgt = (unsigned)(t - RING + 1);  //  lag ~2-3 -> never trips)
        if (cons_seen < tgt) { wait_ge(consf, tgt); cons_seen = tgt; }
      }
      float xnext = 0.f;
      if (tid < 192) xnext = xg[xbase + (t + 1 < T ? t + 1 : t)];

      bf16x8 bfH0[4], bfX;
      #pragma unroll
      for (int kf = 0; kf < 4; ++kf)
        bfH0[kf] = *(const bf16x8*)(lds + p * 4096 + kf * 1024 + rdB);
      bfX = *(const bf16x8*)(lds + LDS_XP + p * 1024 + rdB);

      f32x4 acc[4];
      #pragma unroll
      for (int q = 0; q < 4; ++q) acc[q] = zed;
      #pragma unroll
      for (int kf = 0; kf < 4; ++kf) {
        #pragma unroll
        for (int q = 0; q < 4; ++q)
          acc[q] = __builtin_amdgcn_mfma_f32_16x16x32_bf16(A0[q][kf], bfH0[kf], acc[q], 0, 0, 0);
      }
      #pragma unroll
      for (int q = 0; q < 4; ++q)
        acc[q] = __builtin_amdgcn_mfma_f32_16x16x32_bf16(A0[q][4], bfX, acc[q], 0, 0, 0);

      const unsigned long long hv64 = lstm_ew(acc[0], acc[1], acc[2], acc[3], c0v, h0t);
      *(unsigned long long*)(lds + (1 - p) * 4096 + wrH) = hv64;          // local dbuf
      *(unsigned long long*)(ring + (size_t)(t & (RING - 1)) * SLOT_BYTES + wrH) = hv64;  // stream

      if (tid < 192) {
        const unsigned xp = cvtpk_bf16(xnext, xnext);
        *(unsigned short*)(lds + LDS_XP + (1 - p) * 1024 + wrX) = (unsigned short)xp;
      }
      __syncthreads();
      if (tid == 0)
        __hip_atomic_store(prodf, (unsigned)(t + 1), __ATOMIC_RELEASE, __HIP_MEMORY_SCOPE_AGENT);
    }
    return;
  }

  // ---------------- LAYER 1 CONSUMER ----------------
  // LDS: H1 dbuf at 0 (2x4096), RED at 8192 (2KB)
  bf16x8 A1[4][8];
  f32x4 b1r[4];
  #pragma unroll
  for (int q = 0; q < 4; ++q) {
    const int n = (q * 8 + w) * 16 + lr;
    const float s = (q == 2) ? (2.f * L2E) : (-L2E);
    #pragma unroll
    for (int kf = 0; kf < 4; ++kf) {
      const float* srcA = &Whh1[n * H + kf * 32 + lg * 8];
      const float* srcB = &Wih1[n * H + kf * 32 + lg * 8];
      #pragma unroll
      for (int j = 0; j < 8; ++j) {
        A1[q][kf][j]     = (short)f2bf(srcA[j] * s);
        A1[q][4 + kf][j] = (short)f2bf(srcB[j] * s);
      }
    }
    #pragma unroll
    for (int r = 0; r < 4; ++r) {
      const int nd = (q * 8 + w) * 16 + lg * 4 + r;     // D-frag row for this lane
      b1r[q][r] = (bih1[nd] + bhh1[nd]) * s;
    }
  }
  __syncthreads();

  float c1v[4] = {0.f, 0.f, 0.f, 0.f};
  float h1v[4] = {0.f, 0.f, 0.f, 0.f};
  unsigned prod_seen = 0;

  // warm-up: h0(0)
  wait_ge(prodf, 1); prod_seen = 1;
  bf16x8 h0A[4], h0B[4];
  #pragma unroll
  for (int kf = 0; kf < 4; ++kf)
    h0A[kf] = *(const bf16x8*)(ring + kf * 1024 + rdB);

#define CONS_STEP(TT, P, CUR, NXT)                                              \
  do {                                                                          \
    const int t_ = (TT);                                                        \
    const unsigned need = (unsigned)(((t_ + 2) <= T) ? (t_ + 2) : T);           \
    if (prod_seen < need) { wait_ge(prodf, need); prod_seen = need; }           \
    {                                                                           \
      const int tn = (t_ + 1 < T) ? (t_ + 1) : (T - 1);                         \
      const char* nb = ring + (size_t)(tn & (RING - 1)) * SLOT_BYTES;           \
      _Pragma("unroll")                                                         \
      for (int kf = 0; kf < 4; ++kf)                                            \
        NXT[kf] = *(const bf16x8*)(nb + kf * 1024 + rdB);                       \
    }                                                                           \
    bf16x8 bh1[4];                                                              \
    _Pragma("unroll")                                                           \
    for (int kf = 0; kf < 4; ++kf)                                              \
      bh1[kf] = *(const bf16x8*)(lds + (P) * 4096 + kf * 1024 + rdB);           \
    f32x4 acc[4];                                                               \
    _Pragma("unroll")                                                           \
    for (int q = 0; q < 4; ++q) acc[q] = b1r[q];                                \
    _Pragma("unroll")                                                           \
    for (int kf = 0; kf < 4; ++kf) {                                            \
      _Pragma("unroll")                                                         \
      for (int q = 0; q < 4; ++q) {                                             \
        acc[q] = __builtin_amdgcn_mfma_f32_16x16x32_bf16(A1[q][kf], bh1[kf], acc[q], 0, 0, 0); \
        acc[q] = __builtin_amdgcn_mfma_f32_16x16x32_bf16(A1[q][4 + kf], CUR[kf], acc[q], 0, 0, 0); \
      }                                                                         \
    }                                                                           \
    const unsigned long long hv64 = lstm_ew(acc[0], acc[1], acc[2], acc[3], c1v, h1v); \
    *(unsigned long long*)(lds + (1 - (P)) * 4096 + wrH) = hv64;                \
    __syncthreads();                                                            \
    if (tid == 0 && (((t_ + 1) & 7) == 0))                                      \
      __hip_atomic_store(consf, (unsigned)(t_ + 1), __ATOMIC_RELEASE, __HIP_MEMORY_SCOPE_AGENT); \
  } while (0)

  for (int t = 0; t < T; t += 2) {
    CONS_STEP(t,     0, h0A, h0B);
    CONS_STEP(t + 1, 1, h0B, h0A);
  }
#undef CONS_STEP

  // ---- epilogue: feats = h1(T-1), scores = sigmoid(h1 . Wd + bd) ----
  const float4 wd = *(const float4*)&Wd[bcol];
  const float partial = h1v[0] * wd.x + h1v[1] * wd.y + h1v[2] * wd.z + h1v[3] * wd.w;
  #pragma unroll
  for (int r = 0; r < 4; ++r)
    out[256 + (size_t)(b0 + lr) * H + (bcol + r)] = h1v[r];
  ((float*)(lds + 8192))[tid] = partial;
  __syncthreads();
  if (tid < 16) {
    float s = 0.f;
    #pragma unroll 8
    for (int k = 0; k < 32; ++k) s += ((float*)(lds + 8192))[tid + 16 * k];
    const float v = s + bd[0];
    out[b0 + tid] = __builtin_amdgcn_rcpf(1.f + EXP2(-v * L2E));
  }
}

// ============================ fallback: R2 single kernel ============================
__global__ __launch_bounds__(NTHR, 2) void lstm_single(
    const float* __restrict__ xg,
    const float* __restrict__ Wih0, const float* __restrict__ Whh0,
    const float* __restrict__ bih0, const float* __restrict__ bhh0,
    const float* __restrict__ Wih1, const float* __restrict__ Whh1,
    const float* __restrict__ bih1, const float* __restrict__ bhh1,
    const float* __restrict__ Wd,   const float* __restrict__ bd,
    float* __restrict__ out)
{
  constexpr int LDS_H0 = 0, LDS_H1 = 8192, LDS_X = 16384, LDS_RED = 18432, LDS_SZ = 20480;
  __shared__ char lds[LDS_SZ];
  const int tid = threadIdx.x;
  const int l  = tid & 63;
  const int w  = tid >> 6;
  const int lg = l >> 4;
  const int lr = l & 15;
  const int b0 = blockIdx.x * BPB;

  for (int i = tid; i < LDS_SZ / 4; i += NTHR) ((int*)lds)[i] = 0;
  __syncthreads();
  if (tid < 32) {
    const int buf = tid >> 4, b = tid & 15;
    *(unsigned short*)(lds + LDS_X + buf * 1024 + 256 + b * 16 + 8) = 0x3F80;
  }

  bf16x8 A0[4][5];
  bf16x8 A1[4][8];
  f32x4 b1r[4];
  #pragma unroll
  for (int q = 0; q < 4; ++q) {
    const int n = (q * 8 + w) * 16 + lr;
    const float s = (q == 2) ? (2.f * L2E) : (-L2E);
    #pragma unroll
    for (int kf = 0; kf < 4; ++kf) {
      const float* src = &Whh0[n * H + kf * 32 + lg * 8];
      #pragma unroll
      for (int j = 0; j < 8; ++j) A0[q][kf][j] = (short)f2bf(src[j] * s);
    }
    #pragma unroll
    for (int j = 0; j < 8; ++j) {
      const int k = lg * 8 + j;
      float v = 0.f;
      if (k < CIN) v = Wih0[n * CIN + k] * s;
      else if (k == CIN) v = (bih0[n] + bhh0[n]) * s;
      A0[q][4][j] = (short)f2bf(v);
    }
    #pragma unroll
    for (int kf = 0; kf < 4; ++kf) {
      const float* srcA = &Whh1[n * H + kf * 32 + lg * 8];
      const float* srcB = &Wih1[n * H + kf * 32 + lg * 8];
      #pragma unroll
      for (int j = 0; j < 8; ++j) {
        A1[q][kf][j]     = (short)f2bf(srcA[j] * s);
        A1[q][4 + kf][j] = (short)f2bf(srcB[j] * s);
      }
    }
    #pragma unroll
    for (int r = 0; r < 4; ++r) {
      const int nd = (q * 8 + w) * 16 + lg * 4 + r;
      b1r[q][r] = (bih1[nd] + bhh1[nd]) * s;
    }
  }
  const f32x4 zed = {0.f, 0.f, 0.f, 0.f};

  const int rdB  = lg * 256 + lr * 16;
  const int bcol = w * 16 + lg * 4;
  const int wrH  = (bcol >> 3) * 256 + lr * 16 + (bcol & 7) * 2;
  const int xb = tid & 15, xc = tid >> 4;
  const int wrX = (xc >> 3) * 256 + xb * 16 + (xc & 7) * 2;
  const size_t xbase = (size_t)(b0 + xb) * (CIN * T) + (size_t)xc * T;

  if (tid < 192)
    *(unsigned short*)(lds + LDS_X + wrX) = (unsigned short)f2bf(xg[xbase]);
  __syncthreads();

  float c0v[4] = {0.f, 0.f, 0.f, 0.f};
  float c1v[4] = {0.f, 0.f, 0.f, 0.f};
  float h1v[4] = {0.f, 0.f, 0.f, 0.f};
  float h0t[4];

  #pragma unroll 2
  for (int t = 0; t < T; ++t) {
    const int p = t & 1;
    float xnext = 0.f;
    if (tid < 192) xnext = xg[xbase + (t + 1 < T ? t + 1 : t)];

    f32x4 acc[4];
    #pragma unroll
    for (int q = 0; q < 4; ++q) acc[q] = zed;
    #pragma unroll
    for (int kf = 0; kf < 5; ++kf) {
      const int src = (kf < 4) ? (LDS_H0 + p * 4096 + kf * 1024 + rdB)
                               : (LDS_X + p * 1024 + rdB);
      const bf16x8 bf = *(const bf16x8*)(lds + src);
      #pragma unroll
      for (int q = 0; q < 4; ++q)
        acc[q] = __builtin_amdgcn_mfma_f32_16x16x32_bf16(A0[q][kf], bf, acc[q], 0, 0, 0);
    }
    *(unsigned long long*)(lds + LDS_H0 + (1 - p) * 4096 + wrH) =
        lstm_ew(acc[0], acc[1], acc[2], acc[3], c0v, h0t);
    if (tid < 192) {
      const unsigned xp = cvtpk_bf16(xnext, xnext);
      *(unsigned short*)(lds + LDS_X + (1 - p) * 1024 + wrX) = (unsigned short)xp;
    }
    __syncthreads();

    #pragma unroll
    for (int q = 0; q < 4; ++q) acc[q] = b1r[q];
    #pragma unroll
    for (int kf = 0; kf < 8; ++kf) {
      const int src = (kf < 4)
          ? (LDS_H1 + p * 4096 + kf * 1024 + rdB)
          : (LDS_H0 + (1 - p) * 4096 + (kf - 4) * 1024 + rdB);
      const bf16x8 bf = *(const bf16x8*)(lds + src);
      #pragma unroll
      for (int q = 0; q < 4; ++q)
        acc[q] = __builtin_amdgcn_mfma_f32_16x16x32_bf16(A1[q][kf], bf, acc[q], 0, 0, 0);
    }
    *(unsigned long long*)(lds + LDS_H1 + (1 - p) * 4096 + wrH) =
        lstm_ew(acc[0], acc[1], acc[2], acc[3], c1v, h1v);
    __syncthreads();
  }

  const float4 wd = *(const float4*)&Wd[bcol];
  const float partial = h1v[0] * wd.x + h1v[1] * wd.y + h1v[2] * wd.z + h1v[3] * wd.w;
  #pragma unroll
  for (int r = 0; r < 4; ++r)
    out[256 + (size_t)(b0 + lr) * H + (bcol + r)] = h1v[r];
  ((float*)(lds + LDS_RED))[tid] = partial;
  __syncthreads();
  if (tid < 16) {
    float s = 0.f;
    #pragma unroll 8
    for (int k = 0; k < 32; ++k) s += ((float*)(lds + LDS_RED))[tid + 16 * k];
    const float v = s + bd[0];
    out[b0 + tid] = __builtin_amdgcn_rcpf(1.f + EXP2(-v * L2E));
  }
}

extern "C" void kernel_launch(void* const* d_in, const int* in_sizes, int n_in,
                              void* d_out, int out_size, void* d_ws, size_t ws_size,
                              hipStream_t stream) {
  const float* x    = (const float*)d_in[0];
  // d_in[1] = seq_lengths : unused by the reference
  const float* Wih0 = (const float*)d_in[2];
  const float* Whh0 = (const float*)d_in[3];
  const float* bih0 = (const float*)d_in[4];
  const float* bhh0 = (const float*)d_in[5];
  const float* Wih1 = (const float*)d_in[6];
  const float* Whh1 = (const float*)d_in[7];
  const float* bih1 = (const float*)d_in[8];
  const float* bhh1 = (const float*)d_in[9];
  const float* Wd   = (const float*)d_in[10];
  const float* bd   = (const float*)d_in[11];
  (void)in_sizes; (void)n_in; (void)out_size;

  if (ws_size >= WS_NEED && d_ws != nullptr) {
    lstm_zero_flags<<<dim3(8), dim3(256), 0, stream>>>((unsigned*)d_ws);
    lstm_split<<<dim3(32), dim3(NTHR), 0, stream>>>(
        x, Wih0, Whh0, bih0, bhh0, Wih1, Whh1, bih1, bhh1, Wd, bd,
        (float*)d_out, (char*)d_ws);
  } else {
    lstm_single<<<dim3(16), dim3(NTHR), 0, stream>>>(
        x, Wih0, Whh0, bih0, bhh0, Wih1, Whh1, bih1, bhh1, Wd, bd, (float*)d_out);
  }
}